// Round 2
// baseline (536.430 us; speedup 1.0000x reference)
//
#include <hip/hip_runtime.h>

// Locally-connected conv, MI355X. Round 3b: barrier-free weight streaming.
// (R3a failed to compile: __builtin_nontemporal_load needs a clang
//  ext_vector pointer, not HIP_vector_type<float,4>. Fixed with f32x4.)
// R2 was structure-bound: MfmaUtil 1%, VALUBusy 12%, 2.4 TB/s (38% of
// achievable), WRITE_SIZE 4.2x output (16B partial lines scattered over XCDs).
// R3 structure:
//  - Weights go global -> VGPR directly in MFMA B-frag layout: lane (n,g)
//    reads W[og+n][ks*16+g*8 .. +7] = 2 aligned float4 (nontemporal; pure
//    stream). Each K-step the wave consumes exactly one 64B line per o-row.
//    No weight LDS, no per-chunk barriers, no vmcnt(0) drains in the stream.
//  - x staged once as raw bf16 tile [b][(c+b)&31][y3][xt0..5] (36,864 B).
//    A-frags gathered per step with 8 ds_read_u16; the c-rotation-by-b makes
//    the 32 b-lanes hit 32 distinct banks (9*distinct mod 32, 9 coprime 32).
//  - K = 288 = 18 MFMA steps exactly (no zero pad; R2 wasted 10/80).
//  - 36.9 KB LDS + launch_bounds(256,4) -> 4 blocks/CU = 16 waves/CU.
//  - blockIdx permutation: the 8 sibling blocks (wm=0..7) covering one 128B
//    out line map to the SAME XCD (bids differ by 8) at adjacent slots ->
//    L2 write-combining of the 16B quarters; h clustered per XCD keeps the
//    per-XCD x slice (2.6 MB) L2-resident under the NT weight stream.

typedef __attribute__((ext_vector_type(8))) short short8;
typedef __attribute__((ext_vector_type(16))) float f32x16;
typedef __attribute__((ext_vector_type(4))) float f32x4;

__device__ __forceinline__ unsigned f2bf(float f) {
    unsigned u = __builtin_bit_cast(unsigned, f);
    return (u + 0x7FFFu + ((u >> 16) & 1u)) >> 16;   // RNE, finite inputs
}

__global__ __launch_bounds__(256, 4) void lcconv_kernel(
    const float* __restrict__ xg,    // [32][32][64][64]
    const float* __restrict__ wg,    // [64][64][64][32][3][3]
    const float* __restrict__ bg,    // [64][64][64]
    float* __restrict__ outg)        // [32][64][64][64]
{
    __shared__ unsigned short Xl[32 * 32 * 3 * 6];   // 36,864 B raw x tile

    const int tid  = threadIdx.x;
    const int B    = blockIdx.x;
    // --- XCD-aware permutation (assumes bid%8 round-robin over 8 XCDs)
    const int xcd  = B & 7;
    const int slot = B >> 3;
    const int wm   = slot & 7;                 // member within 128B-line group
    const int gi   = xcd * 32 + (slot >> 3);   // 0..255 group id
    const int h    = gi >> 2;                  // h clustered per XCD
    const int wq2  = (gi >> 1) & 1;
    const int oh   = gi & 1;
    const int w0   = wq2 * 32 + wm * 4;        // 4-wide w strip
    const int og   = oh * 32;

    // ---- build raw x tile once: Xl[b][(c+b)&31][y3][xt], xt -> w = w0-1+xt
#pragma unroll
    for (int t = 0; t < 12; t++) {
        int task = t * 256 + tid;              // 3072 rows of 6 elems
        int b   = task / 96;
        int rem = task - b * 96;
        int c   = rem / 3;
        int y3  = rem - c * 3;
        int y   = h + y3 - 1;
        float v0 = 0.f, v1 = 0.f, v2 = 0.f, v3 = 0.f, v4 = 0.f, v5 = 0.f;
        if ((unsigned)y < 64u) {
            const float* row = xg + ((b * 32 + c) * 64 + y) * 64;
            float4 m = *(const float4*)(row + w0);   // w0 % 4 == 0: aligned
            v1 = m.x; v2 = m.y; v3 = m.z; v4 = m.w;
            if (w0 > 0)      v0 = row[w0 - 1];
            if (w0 + 4 < 64) v5 = row[w0 + 4];
        }
        int cr = (c + b) & 31;
        unsigned* dst = (unsigned*)(Xl + ((b * 32 + cr) * 3 + y3) * 6);
        dst[0] = f2bf(v0) | (f2bf(v1) << 16);
        dst[1] = f2bf(v2) | (f2bf(v3) << 16);
        dst[2] = f2bf(v4) | (f2bf(v5) << 16);
    }
    __syncthreads();

    const int lane = tid & 63;
    const int wv   = tid >> 6;      // wave id == position p (w = w0+wv)
    const int n    = lane & 31;     // A row (b) == B col (o) == C col
    const int g    = lane >> 5;

    const float* wbase = wg
        + (((h * 64) + (w0 + wv)) * 64 + og + n) * 288 + g * 8;

    f32x16 acc;
#pragma unroll
    for (int i = 0; i < 16; i++) acc[i] = 0.f;

    const int abase = n * 576 + wv;   // elem off = b*576 + cr*18 + i*6 + (p+j)

#pragma unroll
    for (int ks = 0; ks < 18; ks++) {
        // B-frag: 8 consecutive k of W row (og+n), stream-once -> NT
        f32x4 wa = __builtin_nontemporal_load((const f32x4*)(wbase + ks * 16));
        f32x4 wb = __builtin_nontemporal_load((const f32x4*)(wbase + ks * 16 + 4));

        // A-frag: gather 8 elems of patch row b=n from raw tile
        short8 a;
        int k0 = ks * 16 + g * 8;
#pragma unroll
        for (int e = 0; e < 8; e++) {
            int k = k0 + e;
            int c = (k * 456) >> 12;        // floor(k/9), exact for k < 288
            int t = k - c * 9;
            int i = (t * 11) >> 5;          // floor(t/3) for t < 9
            int j = t - i * 3;
            int cr = (c + n) & 31;
            a[e] = (short)Xl[abase + cr * 18 + i * 6 + j];
        }

        short8 w8;
        w8[0] = (short)f2bf(wa[0]); w8[1] = (short)f2bf(wa[1]);
        w8[2] = (short)f2bf(wa[2]); w8[3] = (short)f2bf(wa[3]);
        w8[4] = (short)f2bf(wb[0]); w8[5] = (short)f2bf(wb[1]);
        w8[6] = (short)f2bf(wb[2]); w8[7] = (short)f2bf(wb[3]);

        acc = __builtin_amdgcn_mfma_f32_32x32x16_bf16(a, w8, acc, 0, 0, 0);
    }

    // ---- epilogue: C frags -> LDS transpose (reuse Xl) -> float4 stores
    __syncthreads();
    float* outl = (float*)Xl;     // [p][b][o] fp32, 16,384 B
#pragma unroll
    for (int r = 0; r < 16; r++) {
        int row = (r & 3) + 8 * (r >> 2) + 4 * g;   // b (verified C layout)
        outl[(wv * 32 + row) * 32 + n] = acc[r];
    }
    __syncthreads();

#pragma unroll
    for (int it = 0; it < 4; it++) {
        int id = it * 256 + tid;
        int b = id >> 5;
        int o = id & 31;
        float4 v;
        v.x = outl[0 * 1024 + b * 32 + o];
        v.y = outl[1 * 1024 + b * 32 + o];
        v.z = outl[2 * 1024 + b * 32 + o];
        v.w = outl[3 * 1024 + b * 32 + o];
        const float4 bb = *(const float4*)(bg + ((og + o) * 64 + h) * 64 + w0);
        v.x += bb.x; v.y += bb.y; v.z += bb.z; v.w += bb.w;
        *(float4*)(outg + ((b * 64 + og + o) * 64 + h) * 64 + w0) = v;
    }
}

extern "C" void kernel_launch(void* const* d_in, const int* in_sizes, int n_in,
                              void* d_out, int out_size, void* d_ws, size_t ws_size,
                              hipStream_t stream) {
    const float* x = (const float*)d_in[0];
    const float* w = (const float*)d_in[1];
    const float* b = (const float*)d_in[2];
    float* out = (float*)d_out;
    lcconv_kernel<<<dim3(2048), dim3(256), 0, stream>>>(x, w, b, out);
}

// Round 3
// 479.056 us; speedup vs baseline: 1.1198x; 1.1198x over previous
//
#include <hip/hip_runtime.h>

// Locally-connected conv, MI355X. Round 4: global_load_lds weight staging.
// R3 post-mortem: register-direct B-frag loads are 32-lines-per-instruction
// scattered (lane stride 1152B) -> per-CU request concurrency caps BW at
// 1.75 TB/s; all pipes idle (VALU 20%, MFMA 0.9%). Fix = coalesced
// fire-and-forget staging (m97 pattern):
//  - Wave wv stages ITS OWN pos=wv weight rows: 2x global_load_lds_dwordx4
//    per chunk (K_CHUNK=16 floats = 1 MFMA step), fp32 double-buffer in LDS.
//    Each wave reads only what it staged -> NO barriers in the K-loop; a
//    per-wave counted s_waitcnt vmcnt(2) (issue next, wait current) keeps
//    one chunk always in flight.
//  - Bank fix for 64B rows: pre-swizzled GLOBAL slot (m173): phys slot s
//    holds global slot s ^ ((row>>1)&3); reads use the same XOR -> b128
//    reads at the structural 8-phase minimum.
//  - Convert fp32->bf16 at read time (same VALU count as R3).
//  - LDS 36,864 (Xl) + 16,384 (Wb) = 53,248 -> 3 blocks/CU, 12 waves.
//  - Xl raw-tile A-gather (0 conflicts in R3) and epilogue unchanged.

typedef __attribute__((ext_vector_type(8))) short short8;
typedef __attribute__((ext_vector_type(16))) float f32x16;
typedef __attribute__((ext_vector_type(4))) float f32x4;

__device__ __forceinline__ unsigned f2bf(float f) {
    unsigned u = __builtin_bit_cast(unsigned, f);
    return (u + 0x7FFFu + ((u >> 16) & 1u)) >> 16;   // RNE, finite inputs
}

__device__ __forceinline__ void glds16(const float* g, float* l) {
    __builtin_amdgcn_global_load_lds(
        (const __attribute__((address_space(1))) void*)g,
        (__attribute__((address_space(3))) void*)l, 16, 0, 0);
}

__global__ __launch_bounds__(256, 3) void lcconv_kernel(
    const float* __restrict__ xg,    // [32][32][64][64]
    const float* __restrict__ wg,    // [64][64][64][32][3][3]
    const float* __restrict__ bg,    // [64][64][64]
    float* __restrict__ outg)        // [32][64][64][64]
{
    __shared__ float Wb[2][2048];                    // 16,384 B: 2 x 8KB chunk
    __shared__ unsigned short Xl[32 * 32 * 3 * 6];   // 36,864 B raw x tile

    const int tid  = threadIdx.x;
    const int B    = blockIdx.x;
    // --- XCD-aware permutation (bid%8 round-robin over 8 XCDs)
    const int xcd  = B & 7;
    const int slot = B >> 3;
    const int wm   = slot & 7;                 // member within out-line group
    const int gi   = xcd * 32 + (slot >> 3);   // 0..255 group id
    const int h    = gi >> 2;                  // h clustered per XCD
    const int wq2  = (gi >> 1) & 1;
    const int oh   = gi & 1;
    const int w0   = wq2 * 32 + wm * 4;        // 4-wide w strip
    const int og   = oh * 32;

    const int lane = tid & 63;
    const int wv   = tid >> 6;      // wave id == position p (w = w0+wv)
    const int n    = lane & 31;     // A row (b) == B col (o) == C col
    const int g    = lane >> 5;

    // ---- glds sources: wave wv stages pos=wv, 32 o-rows, 2 instrs x 16 rows
    const int o0  = lane >> 2;                         // row within 16-group
    const int gsl = (lane & 3) ^ ((o0 >> 1) & 3);      // pre-swizzled slot
    const float* wrow = wg + ((h * 64 + w0 + wv) * 64 + og) * 288;
    const float* sA = wrow + o0 * 288 + gsl * 4;        // rows o0
    const float* sB = wrow + (16 + o0) * 288 + gsl * 4; // rows 16+o0 (same key)

    // issue chunk 0 before the x prologue (latency hides under it)
    glds16(sA, &Wb[0][wv * 512]);
    glds16(sB, &Wb[0][wv * 512 + 256]);

    // ---- build raw x tile once: Xl[b][(c+b)&31][y3][xt], xt -> w = w0-1+xt
#pragma unroll
    for (int t = 0; t < 12; t++) {
        int task = t * 256 + tid;              // 3072 rows of 6 elems
        int b   = task / 96;
        int rem = task - b * 96;
        int c   = rem / 3;
        int y3  = rem - c * 3;
        int y   = h + y3 - 1;
        float v0 = 0.f, v1 = 0.f, v2 = 0.f, v3 = 0.f, v4 = 0.f, v5 = 0.f;
        if ((unsigned)y < 64u) {
            const float* row = xg + ((b * 32 + c) * 64 + y) * 64;
            float4 m = *(const float4*)(row + w0);   // w0 % 4 == 0: aligned
            v1 = m.x; v2 = m.y; v3 = m.z; v4 = m.w;
            if (w0 > 0)      v0 = row[w0 - 1];
            if (w0 + 4 < 64) v5 = row[w0 + 4];
        }
        int cr = (c + b) & 31;
        unsigned* dst = (unsigned*)(Xl + ((b * 32 + cr) * 3 + y3) * 6);
        dst[0] = f2bf(v0) | (f2bf(v1) << 16);
        dst[1] = f2bf(v2) | (f2bf(v3) << 16);
        dst[2] = f2bf(v4) | (f2bf(v5) << 16);
    }
    __syncthreads();   // Xl visible; also drains chunk-0 glds (full drain)

    f32x16 acc;
#pragma unroll
    for (int i = 0; i < 16; i++) acc[i] = 0.f;

    // read address: row rid = wv*32+n, phys slot = (2g) ^ ((n>>1)&3)
    const int srd   = (wv * 32 + n) * 16 + (((g << 1) ^ ((n >> 1) & 3)) << 2);
    const int abase = n * 576 + wv;   // elem off = b*576 + cr*18 + i*6 + (p+j)

#pragma unroll
    for (int c = 0; c < 18; c++) {
        // T4 counted-vmcnt: issue chunk c+1, then wait only for chunk c
        if (c < 17) {
            glds16(sA + (c + 1) * 16, &Wb[(c + 1) & 1][wv * 512]);
            glds16(sB + (c + 1) * 16, &Wb[(c + 1) & 1][wv * 512 + 256]);
            asm volatile("s_waitcnt vmcnt(2)" ::: "memory");
        } else {
            asm volatile("s_waitcnt vmcnt(0)" ::: "memory");
        }
        __builtin_amdgcn_sched_barrier(0);   // rule 18: pin reads after wait

        f32x4 wa  = *(const f32x4*)&Wb[c & 1][srd];
        f32x4 wb4 = *(const f32x4*)&Wb[c & 1][srd ^ 4];

        // A-frag: gather 8 elems of patch row b=n from raw tile
        short8 a;
        int k0 = c * 16 + g * 8;
#pragma unroll
        for (int e = 0; e < 8; e++) {
            int k = k0 + e;
            int cc = (k * 456) >> 12;       // floor(k/9), exact for k < 288
            int t = k - cc * 9;
            int i = (t * 11) >> 5;          // floor(t/3) for t < 9
            int j = t - i * 3;
            int cr = (cc + n) & 31;
            a[e] = (short)Xl[abase + cr * 18 + i * 6 + j];
        }

        short8 w8;
        w8[0] = (short)f2bf(wa[0]);  w8[1] = (short)f2bf(wa[1]);
        w8[2] = (short)f2bf(wa[2]);  w8[3] = (short)f2bf(wa[3]);
        w8[4] = (short)f2bf(wb4[0]); w8[5] = (short)f2bf(wb4[1]);
        w8[6] = (short)f2bf(wb4[2]); w8[7] = (short)f2bf(wb4[3]);

        acc = __builtin_amdgcn_mfma_f32_32x32x16_bf16(a, w8, acc, 0, 0, 0);
    }

    // ---- epilogue: C frags -> LDS transpose (reuse Xl) -> float4 stores
    __syncthreads();
    float* outl = (float*)Xl;     // [p][b][o] fp32, 16,384 B
#pragma unroll
    for (int r = 0; r < 16; r++) {
        int row = (r & 3) + 8 * (r >> 2) + 4 * g;   // b (verified C layout)
        outl[(wv * 32 + row) * 32 + n] = acc[r];
    }
    __syncthreads();

#pragma unroll
    for (int it = 0; it < 4; it++) {
        int id = it * 256 + tid;
        int b = id >> 5;
        int o = id & 31;
        float4 v;
        v.x = outl[0 * 1024 + b * 32 + o];
        v.y = outl[1 * 1024 + b * 32 + o];
        v.z = outl[2 * 1024 + b * 32 + o];
        v.w = outl[3 * 1024 + b * 32 + o];
        const float4 bb = *(const float4*)(bg + ((og + o) * 64 + h) * 64 + w0);
        v.x += bb.x; v.y += bb.y; v.z += bb.z; v.w += bb.w;
        *(float4*)(outg + ((b * 64 + og + o) * 64 + h) * 64 + w0) = v;
    }
}

extern "C" void kernel_launch(void* const* d_in, const int* in_sizes, int n_in,
                              void* d_out, int out_size, void* d_ws, size_t ws_size,
                              hipStream_t stream) {
    const float* x = (const float*)d_in[0];
    const float* w = (const float*)d_in[1];
    const float* b = (const float*)d_in[2];
    float* out = (float*)d_out;
    lcconv_kernel<<<dim3(2048), dim3(256), 0, stream>>>(x, w, b, out);
}

// Round 4
// 469.894 us; speedup vs baseline: 1.1416x; 1.0195x over previous
//
#include <hip/hip_runtime.h>

// Locally-connected conv, MI355X. Round 5: sequential weight streaming.
// R2/R3/R4 all pinned at ~1.8-2.4 TB/s with K-minor weight reads (<=64B
// DRAM granules at 1152B stride). Fix: stream each contiguous 36,864B
// weight half-tile (one (pos, o-half): 32 rows x 1152B) SEQUENTIALLY into
// LDS via 36 fully-coalesced 1KB global_load_lds, ring-2 phase pipeline;
// consume K-minor from LDS.
//  - Block = (h, 4-pos w strip) x all 64 o -> 8 phases of one half-tile.
//  - 4 waves = (oh, kh): waves with oh==phase&1 compute K=144 each
//    (9 MFMA steps); kh pair reduced through LDS each phase (acc is a
//    single f32x16; pos-complete every phase -> no runtime acc indexing).
//  - glds src pre-swizzled within 128B windows (q ^= row&7) so B-frag
//    ds-reads are ~4-way max; dest linear (HW requirement).
//  - Phase ~3600cy at fair-share BW >> HBM latency -> plain __syncthreads
//    ring-2 works (vmcnt drain hits after data landed).
//  - LDS 147,456B: ring 2x36,864 + Xl 36,864 + Pred 4,096 + outF 32,768.
//    1 block/CU. Grid 1024 (halves x-prologue traffic vs R4).
//  - XCD map: all 16 ws of an h on one XCD, adjacent slots -> L2 merges
//    the 16B out-line quarters; per-XCD x slice L2-resident.

typedef __attribute__((ext_vector_type(8))) short short8;
typedef __attribute__((ext_vector_type(16))) float f32x16;
typedef __attribute__((ext_vector_type(4))) float f32x4;

__device__ __forceinline__ unsigned f2bf(float f) {
    unsigned u = __builtin_bit_cast(unsigned, f);
    return (u + 0x7FFFu + ((u >> 16) & 1u)) >> 16;   // RNE, finite inputs
}

__device__ __forceinline__ void glds16(const float* g, float* l) {
    __builtin_amdgcn_global_load_lds(
        (const __attribute__((address_space(1))) void*)g,
        (__attribute__((address_space(3))) void*)l, 16, 0, 0);
}

__global__ __launch_bounds__(256, 1) void lcconv_kernel(
    const float* __restrict__ xg,    // [32][32][64][64]
    const float* __restrict__ wg,    // [64][64][64][32][3][3]
    const float* __restrict__ bg,    // [64][64][64]
    float* __restrict__ outg)        // [32][64][64][64]
{
    __shared__ __align__(16) unsigned char Lds[147456];
    float*          Wring = (float*)Lds;                     // 2 x 36,864 B
    unsigned short* Xl    = (unsigned short*)(Lds + 73728);  // 36,864 B
    float*          Pred  = (float*)(Lds + 110592);          // 4,096 B
    float*          outF  = (float*)(Lds + 114688);          // 32,768 B
    (void)Wring;

    const int tid = threadIdx.x;
    const int Bq  = blockIdx.x;
    // all 16 ws of one h land on one XCD in adjacent slots
    const int xcd = Bq & 7;
    const int idx = Bq >> 3;                 // 0..127
    const int h   = xcd * 8 + (idx >> 4);
    const int w0  = (idx & 15) * 4;

    const int lane = tid & 63;
    const int wv   = tid >> 6;
    const int n    = lane & 31;
    const int g    = lane >> 5;
    const int oh   = wv >> 1;                // which o-half this wave computes
    const int kh   = wv & 1;                 // which K-half (144 each)

    // per-lane glds source byte offsets within a 36,864B half-tile region.
    // phys 16B slot P holds global slot r*72 + (q ^ (r&7)) (involution).
    int srcoff[9];
#pragma unroll
    for (int j = 0; j < 9; j++) {
        int P  = wv * 576 + j * 64 + lane;
        int rp = (P * 3641) >> 18;           // floor(P/72), exact for P<32768
        int qp = P - rp * 72;
        srcoff[j] = rp * 1152 + ((qp ^ (rp & 7)) << 4);
    }

    // issue phase 0 (pos 0, oh 0) into ring slot 0; x-build's syncthreads drains it
    {
        const char* rb = (const char*)(wg + ((h * 64 + w0) * 64) * 288);
        float* db = (float*)(Lds + wv * 9216);
#pragma unroll
        for (int j = 0; j < 9; j++)
            glds16((const float*)(rb + srcoff[j]), db + j * 256);
    }

    // ---- build raw x tile once: Xl[b][(c+b)&31][y3][xt], xt -> w = w0-1+xt
#pragma unroll
    for (int t = 0; t < 12; t++) {
        int task = t * 256 + tid;            // 3072 rows of 6 elems
        int b   = task / 96;
        int rem = task - b * 96;
        int c   = rem / 3;
        int y3  = rem - c * 3;
        int y   = h + y3 - 1;
        float v0 = 0.f, v1 = 0.f, v2 = 0.f, v3 = 0.f, v4 = 0.f, v5 = 0.f;
        if ((unsigned)y < 64u) {
            const float* row = xg + ((b * 32 + c) * 64 + y) * 64;
            float4 m = *(const float4*)(row + w0);   // w0 % 4 == 0: aligned
            v1 = m.x; v2 = m.y; v3 = m.z; v4 = m.w;
            if (w0 > 0)      v0 = row[w0 - 1];
            if (w0 + 4 < 64) v5 = row[w0 + 4];
        }
        int cr = (c + b) & 31;
        unsigned* dst = (unsigned*)(Xl + ((b * 32 + cr) * 3 + y3) * 6);
        dst[0] = f2bf(v0) | (f2bf(v1) << 16);
        dst[1] = f2bf(v2) | (f2bf(v3) << 16);
        dst[2] = f2bf(v4) | (f2bf(v5) << 16);
    }
    __syncthreads();

    f32x16 acc;
#pragma unroll
    for (int i = 0; i < 16; i++) acc[i] = 0.f;

    const int kh144  = kh * 144, kh36 = kh * 36;
    const int g8     = g * 8,    g2   = g * 2;
    const int nn1152 = n * 1152, n7   = n & 7;

    for (int ph = 0; ph < 8; ph++) {
        __syncthreads();   // phase ph data landed (vmcnt drain); slot (ph+1)&1 free

        if (ph < 7) {      // stage next half-tile into the other ring slot
            int p1 = ph + 1;
            const char* rb = (const char*)(
                wg + ((h * 64 + w0 + (p1 >> 1)) * 64 + (p1 & 1) * 32) * 288);
            float* db = (float*)(Lds + (p1 & 1) * 36864 + wv * 9216);
#pragma unroll
            for (int j = 0; j < 9; j++)
                glds16((const float*)(rb + srcoff[j]), db + j * 256);
        }

        const int active = (oh == (ph & 1));
        const int pos    = ph >> 1;
        if (active) {
            const char* Wt = (const char*)Lds + (ph & 1) * 36864;
            const int   ab = n * 576 + pos;
#pragma unroll
            for (int s = 0; s < 9; s++) {
                int q0 = kh36 + s * 4 + g2;          // even -> pair {q0,q0+1}
                f32x4 wa = *(const f32x4*)(Wt + nn1152 + (((q0    ) ^ n7) << 4));
                f32x4 wb = *(const f32x4*)(Wt + nn1152 + (((q0 + 1) ^ n7) << 4));

                short8 a;
#pragma unroll
                for (int e = 0; e < 8; e++) {
                    int k  = kh144 + s * 16 + g8 + e;
                    int c  = (k * 456) >> 12;        // floor(k/9), k < 288
                    int t2 = k - c * 9;
                    int i  = (t2 * 11) >> 5;         // floor(t2/3), t2 < 9
                    int j2 = t2 - i * 3;
                    int cr = (c + n) & 31;
                    a[e] = (short)Xl[ab + cr * 18 + i * 6 + j2];
                }

                short8 w8;
                w8[0] = (short)f2bf(wa[0]); w8[1] = (short)f2bf(wa[1]);
                w8[2] = (short)f2bf(wa[2]); w8[3] = (short)f2bf(wa[3]);
                w8[4] = (short)f2bf(wb[0]); w8[5] = (short)f2bf(wb[1]);
                w8[6] = (short)f2bf(wb[2]); w8[7] = (short)f2bf(wb[3]);

                acc = __builtin_amdgcn_mfma_f32_32x32x16_bf16(a, w8, acc, 0, 0, 0);
            }
            if (kh == 0) {   // stash partial for partner
#pragma unroll
                for (int r = 0; r < 16; r++) Pred[r * 64 + lane] = acc[r];
            }
        }
        __syncthreads();   // Pred visible to kh=1 partner

        if (active && kh == 1) {
#pragma unroll
            for (int r = 0; r < 16; r++) {
                float v = acc[r] + Pred[r * 64 + lane];
                int b = (r & 3) + 8 * (r >> 2) + 4 * g;   // verified C layout
                outF[((oh * 4 + pos) * 32 + b) * 32 + n] = v;
            }
        }
        if (active) {
#pragma unroll
            for (int i2 = 0; i2 < 16; i2++) acc[i2] = 0.f;
        }
    }
    __syncthreads();

    // ---- final stores: float4 along w (pos 0..3), + bias
#pragma unroll
    for (int it = 0; it < 8; it++) {
        int id = it * 256 + tid;
        int b  = id >> 6;
        int o  = id & 63;
        const float* src = outF + (o >> 5) * 4096 + b * 32 + (o & 31);
        float4 v;
        v.x = src[0];
        v.y = src[1024];
        v.z = src[2048];
        v.w = src[3072];
        const float4 bb = *(const float4*)(bg + (o * 64 + h) * 64 + w0);
        v.x += bb.x; v.y += bb.y; v.z += bb.z; v.w += bb.w;
        *(float4*)(outg + ((b * 64 + o) * 64 + h) * 64 + w0) = v;
    }
}

extern "C" void kernel_launch(void* const* d_in, const int* in_sizes, int n_in,
                              void* d_out, int out_size, void* d_ws, size_t ws_size,
                              hipStream_t stream) {
    const float* x = (const float*)d_in[0];
    const float* w = (const float*)d_in[1];
    const float* b = (const float*)d_in[2];
    float* out = (float*)d_out;
    lcconv_kernel<<<dim3(1024), dim3(256), 0, stream>>>(x, w, b, out);
}